// Round 5
// baseline (62.708 us; speedup 1.0000x reference)
//
#include <hip/hip_runtime.h>

// Problem constants (from reference): B=32, T=1024, D=1024, N_ITER=256, SR=4
#define BB 32
#define TT 1024
#define DD 1024
#define NIT 256
#define SRR 4
#define KT 16            // output rows per block
#define SLDA 261         // slab row stride (261 % 32 = 5 -> 16-lane conflict-free)

typedef float vf4 __attribute__((ext_vector_type(4)));   // native vec for nt-store

// ---------------------------------------------------------------------------
// Fused kernel: block = 16 consecutive t of one b (2048 blocks, 256 threads).
// Phase 1: stage ds[b, t0..t0+16, :] (17 rows x 256 steps) into LDS; 16 lanes
//   run the serial Euler chain (1 fma + clamp per step, fast path i0 == r0
//   with 'bad'-flag fallback to the exact general gather — never taken for
//   the bench data). f -> LDS + out_f.
// Phase 2: all 256 threads compute 16 Catmull-Rom rows; row indices computed
//   from f directly (uniform per k), 4x float4 loads (intra-block L2 reuse),
//   nontemporal stores. Oversubscription (4+ blocks/CU) overlaps late blocks'
//   phase 1 with early blocks' phase 2 streaming.
// ---------------------------------------------------------------------------
__global__ __launch_bounds__(256, 4) void fused_kernel(const float* __restrict__ xs,
                                                       const float* __restrict__ ds,
                                                       float* __restrict__ out_ys,
                                                       float* __restrict__ f_out) {
    __shared__ float slab[(KT + 1) * SLDA];   // 17 rows x 261 floats, 17.7 KB
    __shared__ float fbuf[KT];

    // bijective chunked XCD swizzle over 2048 blocks (2048 % 8 == 0)
    const int nwg = BB * (TT / KT);
    const int blk = (blockIdx.x & 7) * (nwg >> 3) + (blockIdx.x >> 3);
    const int b  = blk >> 6;                  // 64 blocks per batch
    const int t0 = (blk & 63) * KT;
    const int tid = threadIdx.x;
    const float inv = 1.0f / (float)(NIT * SRR);   // 1/1024, exact

    // ---- Phase 1a: stage ds rows t0..t0+16 into LDS (coalesced float4) ----
    const float4* dsv = (const float4*)ds;
#pragma unroll
    for (int it = 0; it < 5; ++it) {
        const int idx = it * 256 + tid;       // 17*64 = 1088 float4 total
        if (idx < (KT + 1) * (NIT / 4)) {
            const int r = idx >> 6, q = idx & 63;
            const int row = min(t0 + r, TT - 1);
            const float4 v = dsv[((size_t)(b * TT + row) << 6) + q];
            float* s = slab + r * SLDA + q * 4;
            s[0] = v.x; s[1] = v.y; s[2] = v.z; s[3] = v.w;
        }
    }
    __syncthreads();

    // ---- Phase 1b: 16-lane serial ODE chains ----
    if (tid < KT) {
        const int t  = t0 + tid;
        const int r0 = (t < TT - 2) ? t : (TT - 2);
        const int ia = r0 - t0;               // slab row of d0
        const float lo = -(float)r0;
        const float hi = (float)(TT - 1 - r0);
        const bool edge = (r0 == TT - 2);

        float f0 = (float)t + slab[tid * SLDA] * inv;   // ds[b,t,0]
        f0 = fminf(fmaxf(f0, 0.0f), (float)(TT - 1));
        float g = f0 - (float)r0;
        bool bad = false;

        const float* s0 = slab + ia * SLDA;
        const float* s1 = s0 + SLDA;
#pragma unroll 8
        for (int i = 1; i < NIT; ++i) {
            const float d0 = s0[i] * inv;
            const float d1 = s1[i] * inv;
            g = fmaf(g, 1.0f + (d1 - d0), d0);           // 1-fma chain
            g = fminf(fmaxf(g, lo), hi);                 // ref's clip
            bad |= (g < 0.0f) | ((g >= 1.0f) & !(edge & (g == hi)));
        }

        float fres = (float)r0 + g;
        if (bad) {   // exact general path (exec-masked off for bench data)
            float f = (float)t + ds[(size_t)(b * TT + t) * NIT] * inv;
            f = fminf(fmaxf(f, 0.0f), (float)(TT - 1));
            for (int i = 1; i < NIT; ++i) {
                int i0 = (int)floorf(f);
                i0 = min(max(i0, 0), TT - 2);
                const float d0 = ds[(size_t)(b * TT + i0) * NIT + i] * inv;
                const float d1 = ds[(size_t)(b * TT + i0 + 1) * NIT + i] * inv;
                const float tf = f - (float)i0;
                f = fminf(fmaxf(f + d0 + tf * (d1 - d0), 0.0f), (float)(TT - 1));
            }
            fres = f;
        }
        fbuf[tid] = fres;
        f_out[b * TT + t] = fres;
    }
    __syncthreads();

    // ---- Phase 2: 16 Catmull-Rom rows ----
    const float4* X = (const float4*)xs + (size_t)b * TT * (DD / 4);
    vf4* O = (vf4*)out_ys;

    for (int k = 0; k < KT; ++k) {
        const float fv = fbuf[k];
        int i1 = (int)floorf(fv);
        i1 = min(max(i1, 0), TT - 1);
        const float tf = fv - (float)i1;
        const float t2 = tf * tf, t3 = t2 * tf;
        const float w0 = -0.5f * t3 + t2 - 0.5f * tf;
        const float w1 = 1.5f * t3 - 2.5f * t2 + 1.0f;
        const float w2 = -1.5f * t3 + 2.0f * t2 + 0.5f * tf;
        const float w3 = 0.5f * t3 - 0.5f * t2;

        const int j0 = max(i1 - 1, 0);
        const int j2 = min(i1 + 1, TT - 1);
        const int j3 = min(i1 + 2, TT - 1);

        const float4 p0 = X[((size_t)j0 << 8) + tid];
        const float4 p1 = X[((size_t)i1 << 8) + tid];
        const float4 p2 = X[((size_t)j2 << 8) + tid];
        const float4 p3 = X[((size_t)j3 << 8) + tid];
        vf4 v;
        v.x = w0 * p0.x + w1 * p1.x + w2 * p2.x + w3 * p3.x;
        v.y = w0 * p0.y + w1 * p1.y + w2 * p2.y + w3 * p3.y;
        v.z = w0 * p0.z + w1 * p1.z + w2 * p2.z + w3 * p3.z;
        v.w = w0 * p0.w + w1 * p1.w + w2 * p2.w + w3 * p3.w;
        __builtin_nontemporal_store(v, O + (((size_t)(b * TT + t0 + k)) << 8) + tid);
    }
}

extern "C" void kernel_launch(void* const* d_in, const int* in_sizes, int n_in,
                              void* d_out, int out_size, void* d_ws, size_t ws_size,
                              hipStream_t stream) {
    const float* xs = (const float*)d_in[0];   // (B, T, D) f32
    const float* ds = (const float*)d_in[1];   // (B, T, N_ITER) f32

    float* out_ys = (float*)d_out;                     // (B, T, D)
    float* out_f  = out_ys + (size_t)BB * TT * DD;     // (B, T)

    fused_kernel<<<dim3(BB * (TT / KT)), 256, 0, stream>>>(xs, ds, out_ys, out_f);
}